// Round 10
// baseline (4499.953 us; speedup 1.0000x reference)
//
#include <hip/hip_runtime.h>
#include <stdint.h>
#include <math.h>

// ---------------------------------------------------------------------------
// Transformer forward, MI355X. bf16 MFMA operands, fp32 accum, fp32 residual.
// GEMM: C[M,N] = A[M,K] x Bt[N,K]^T, both K-major bf16.
// K-dim of all GEMM inputs stored PERMUTED within each 32-block:
//   k = 32*kk + 16*hi + 4*g + o  ->  p = 32*kk + 8*g + 4*hi + o
// so one MFMA fragment = one contiguous 16B chunk -> single ds_read_b128.
// Chunks XOR-swizzled by row&7 (pre-swizzled global source; linear LDS dest).
// qkv_attn: swapped QK^T (S^T = K@Q^T) -> P stays in registers; V-epilogue
// packs 4 consecutive key-slots into one ds_write_b64.
// Mc=32768: live set (n+o+act+h ~150MB) L3-resident. 65536 -> 301MB thrash
// (R8). Gated at (256,3): R8 showed occupancy 21->30% from this alone.
// ---------------------------------------------------------------------------

#define LAYERS 6
#define BATCH  2048
#define SEQ    64
#define DMODEL 256
#define NHEAD  8
#define INNERD 512
#define FFDIM  1024
#define VOCAB  100
#define MTOK   (BATCH*SEQ)
#define MCAP   32768

typedef unsigned short u16;
typedef __attribute__((ext_vector_type(4))) float f32x4;
typedef __attribute__((ext_vector_type(4))) short s16x4;
typedef __attribute__((ext_vector_type(8))) short s16x8;

__device__ inline u16 f2bf(float f){
  union { float f; unsigned int u; } x; x.f = f;
  unsigned int u = x.u;
  return (u16)((u + 0x7fffu + ((u >> 16) & 1u)) >> 16);
}

__device__ inline void gload16(const void* g, void* l){
  __builtin_amdgcn_global_load_lds(
      (const __attribute__((address_space(1))) unsigned int*)g,
      (__attribute__((address_space(3))) unsigned int*)l, 16, 0, 0);
}

__device__ inline f32x4 mfma16(s16x8 a, s16x8 b, f32x4 c){
  return __builtin_amdgcn_mfma_f32_16x16x32_bf16(a, b, c, 0, 0, 0);
}

// fragment = one 16B chunk (permuted layout), single ds_read_b128
__device__ inline s16x8 ldfrag(const u16* lds, int row, int kk, int g){
  int chunk = ((kk<<2)|g) ^ (row&7);
  return *(const s16x8*)(lds + row*64 + chunk*8);
}

// permuted column index for within-32-block k remap (writers)
__device__ inline int pcol32(int col_base32, int hi, int g, int o){
  return col_base32 | (g<<3) | (hi<<2) | o;
}

// ---------------------------------------------------------------------------
// weight convert+transpose+permute: out[l][n][p(k)] = bf16(in[l][k][n])
// ---------------------------------------------------------------------------
__global__ __launch_bounds__(256) void wtrans_kernel(
    const float* __restrict__ in, u16* __restrict__ out, int K, int N, int total)
{
  int idx = blockIdx.x*256 + threadIdx.x;
  if (idx >= total) return;
  int l = idx / (N*K);
  int r = idx - l*(N*K);
  int n = r / K;
  int k = r - n*K;
  int p = (k & ~31) | (((k>>2)&3)<<3) | (((k>>4)&1)<<2) | (k&3);
  out[(size_t)l*N*K + (size_t)n*K + p] = f2bf(in[(size_t)l*K*N + (size_t)k*N + n]);
}

// ---------------------------------------------------------------------------
// embed + ln1[0]: h = E-gather (fp32), n = LN(h) (bf16, permuted)
// ---------------------------------------------------------------------------
__global__ __launch_bounds__(256) void embed_ln_kernel(
    const int* __restrict__ x, const float* __restrict__ E,
    const float* __restrict__ gam, const float* __restrict__ bet,
    float* __restrict__ h, u16* __restrict__ nout)
{
  int t = threadIdx.x;
  int m = blockIdx.x*4 + (t>>6);
  int lane = t & 63;
  int s = m & 63;
  int tok = x[m];
  const float4 v = *(const float4*)(E + ((size_t)s*VOCAB + tok)*DMODEL + lane*4);
  *(float4*)(h + (size_t)m*DMODEL + lane*4) = v;
  float su = v.x+v.y+v.z+v.w;
  float q  = v.x*v.x+v.y*v.y+v.z*v.z+v.w*v.w;
  #pragma unroll
  for (int mask=1; mask<64; mask<<=1){
    su += __shfl_xor(su, mask);
    q  += __shfl_xor(q,  mask);
  }
  float mean = su*(1.f/256.f);
  float var  = q*(1.f/256.f) - mean*mean;
  float rs   = rsqrtf(var + 1e-5f);
  const float4 gv = *(const float4*)(gam + lane*4);
  const float4 bv = *(const float4*)(bet + lane*4);
  ushort4 ov;
  ov.x = f2bf((v.x-mean)*rs*gv.x + bv.x);
  ov.y = f2bf((v.y-mean)*rs*gv.y + bv.y);
  ov.z = f2bf((v.z-mean)*rs*gv.z + bv.z);
  ov.w = f2bf((v.w-mean)*rs*gv.w + bv.w);
  int p4 = (lane>>3)*32 + (lane&3)*8 + ((lane>>2)&1)*4;   // permuted base
  *(ushort4*)(nout + (size_t)m*DMODEL + p4) = ov;
}

// ---------------------------------------------------------------------------
// FUSED QKV GEMM + attention. Block = 128 tokens (2 seqs) x 1 head, 4 waves.
// setprio(1) wraps MFMA clusters. V-epilogue: one ds_write_b64 per (i,j)
// (4 consecutive permuted key slots; kb = token-base & 63 is 4-aligned).
// ---------------------------------------------------------------------------
__global__ __launch_bounds__(256, 3) void qkv_attn_kernel(
    const u16* __restrict__ A, const u16* __restrict__ Bt,
    u16* __restrict__ o, int K)
{
  __shared__ __align__(16) u16 smem[24576];   // 49152 B
  u16* As = smem;            // [128][64] GEMM staging
  u16* Bs = smem + 8192;     // [192][64] GEMM staging
  u16* qs = smem;            // [128 tok][64 d]   permuted chunks, overlays As
  u16* ks = smem + 8192;     // [128 tok][64 d]   overlays Bs
  u16* vt = smem + 16384;    // [seq*64+d][64 key] permuted chunks

  const int t = threadIdx.x;
  const int w = t >> 6, lane = t & 63, g = lane >> 4, c = lane & 15;
  const int cpx = gridDim.x >> 3;
  const int wg = (blockIdx.x & 7)*cpx + (blockIdx.x >> 3);
  const int hh = wg & 7;
  const int m0 = (wg >> 3) * 128;

  // ---- phase 1: GEMM. wave = 32-row strip x 192 cols. acc[2][12].
  f32x4 acc[2][12];
  #pragma unroll
  for (int i=0;i<2;++i)
    #pragma unroll
    for (int j=0;j<12;++j){ f32x4 z = {0.f,0.f,0.f,0.f}; acc[i][j] = z; }

  const int nkt = K >> 6;   // 4
  for (int kt = 0; kt < nkt; ++kt){
    #pragma unroll
    for (int i=0;i<4;++i){   // A: 128 rows x 8 chunks
      int cid = (i*4 + w)*64 + lane;
      int row = cid >> 3, seg = cid & 7;
      gload16(A + (size_t)(m0+row)*K + (size_t)kt*64 + ((seg ^ (row&7))<<3),
              As + cid*8);
    }
    #pragma unroll
    for (int i=0;i<6;++i){   // B: 192 rows (q|k|v of head hh) x 8 chunks
      int cid = (i*4 + w)*64 + lane;
      int brow = cid >> 3, seg = cid & 7;
      int ng = (brow>>6)*512 + hh*64 + (brow & 63);
      gload16(Bt + (size_t)ng*K + (size_t)kt*64 + ((seg ^ (brow&7))<<3),
              Bs + cid*8);
    }
    asm volatile("s_waitcnt vmcnt(0)" ::: "memory");
    __syncthreads();
    __builtin_amdgcn_s_setprio(1);
    #pragma unroll
    for (int kk=0; kk<2; ++kk){
      s16x8 af[2];
      #pragma unroll
      for (int i=0;i<2;++i) af[i] = ldfrag(As, w*32 + i*16 + c, kk, g);
      #pragma unroll
      for (int j=0;j<12;++j){
        s16x8 bf = ldfrag(Bs, j*16 + c, kk, g);
        acc[0][j] = mfma16(af[0], bf, acc[0][j]);
        acc[1][j] = mfma16(af[1], bf, acc[1][j]);
      }
    }
    __builtin_amdgcn_s_setprio(0);
    __syncthreads();
  }

  // ---- epilogue: quantize, scatter into permuted+XOR q/k/v LDS tiles
  // q/k: scalar (rows differ per r). V: r=0..3 -> 4 consecutive key slots
  //      (pos = hi*4 + r within chunk) -> one b64 write.
  #pragma unroll
  for (int i=0;i<2;++i){
    #pragma unroll
    for (int j=0;j<8;++j){
      #pragma unroll
      for (int r=0;r<4;++r){
        int tl = w*32 + i*16 + g*4 + r;
        u16 val = f2bf(acc[i][j][r]);
        int chunk = ((j&3)>>1)*4 + (c>>2);
        int pos   = (j&1)*4 + (c&3);
        u16* base = (j < 4) ? qs : ks;
        base[tl*64 + ((chunk ^ (tl&7))<<3) + pos] = val;
      }
    }
    #pragma unroll
    for (int j=8;j<12;++j){
      int tlb = w*32 + i*16 + g*4;          // token base, = 0 mod 4
      int d = (j-8)*16 + c;
      int row = (tlb & 64) + d;
      int kb = tlb & 63;
      int chunk = ((kb>>5)<<2) | ((kb>>2)&3);
      int hi = (kb>>4)&1;
      union { s16x4 v; u16 e[4]; } u;
      #pragma unroll
      for (int r=0;r<4;++r) u.e[r] = f2bf(acc[i][j][r]);
      *(s16x4*)(vt + row*64 + ((chunk ^ (row&7))<<3) + hi*4) = u.v;
    }
  }
  __syncthreads();

  // ---- phase 2: attention (32 queries/wave, seq = w>>1)
  const int seq = w >> 1;
  const int qrow = w*32;

  // S^T = K @ Q^T : sc[jk][iq], lane (g,c) holds keys jk*16+4g+{0..3}
  // for query iq*16+c.
  f32x4 sc[4][2];
  #pragma unroll
  for (int jk=0;jk<4;++jk){ f32x4 z = {0.f,0.f,0.f,0.f}; sc[jk][0]=z; sc[jk][1]=z; }
  __builtin_amdgcn_s_setprio(1);
  #pragma unroll
  for (int kk=0;kk<2;++kk){
    s16x8 qf0 = ldfrag(qs, qrow + c,      kk, g);
    s16x8 qf1 = ldfrag(qs, qrow + 16 + c, kk, g);
    #pragma unroll
    for (int jk=0;jk<4;++jk){
      s16x8 kf = ldfrag(ks, seq*64 + jk*16 + c, kk, g);
      sc[jk][0] = mfma16(kf, qf0, sc[jk][0]);
      sc[jk][1] = mfma16(kf, qf1, sc[jk][1]);
    }
  }
  __builtin_amdgcn_s_setprio(0);

  // softmax fully in registers; P packs directly into PV A-fragments
  s16x8 af[2][2];
  #pragma unroll
  for (int iq=0;iq<2;++iq){
    float mx = sc[0][iq][0];
    #pragma unroll
    for (int jk=0;jk<4;++jk)
      #pragma unroll
      for (int r=0;r<4;++r) mx = fmaxf(mx, sc[jk][iq][r]);
    mx = fmaxf(mx, __shfl_xor(mx, 16));
    mx = fmaxf(mx, __shfl_xor(mx, 32));
    float p[4][4];
    float sm = 0.f;
    #pragma unroll
    for (int jk=0;jk<4;++jk)
      #pragma unroll
      for (int r=0;r<4;++r){
        float e = expf((sc[jk][iq][r]-mx)*0.125f);
        p[jk][r] = e; sm += e;
      }
    sm += __shfl_xor(sm, 16);
    sm += __shfl_xor(sm, 32);
    float inv = 1.f/sm;
    #pragma unroll
    for (int kk=0;kk<2;++kk){
      union { s16x8 v; u16 e[8]; } u;
      #pragma unroll
      for (int oo=0;oo<4;++oo){
        u.e[oo]   = f2bf(p[2*kk  ][oo]*inv);   // key 32kk+4g+oo
        u.e[4+oo] = f2bf(p[2*kk+1][oo]*inv);   // key 32kk+16+4g+oo
      }
      af[iq][kk] = u.v;
    }
  }

  // O = P @ V
  f32x4 oa[2][4];
  #pragma unroll
  for (int jd=0;jd<4;++jd){ f32x4 z = {0.f,0.f,0.f,0.f}; oa[0][jd]=z; oa[1][jd]=z; }
  __builtin_amdgcn_s_setprio(1);
  #pragma unroll
  for (int kk=0;kk<2;++kk)
    #pragma unroll
    for (int jd=0;jd<4;++jd){
      s16x8 vf = ldfrag(vt, seq*64 + jd*16 + c, kk, g);
      oa[0][jd] = mfma16(af[0][kk], vf, oa[0][jd]);
      oa[1][jd] = mfma16(af[1][kk], vf, oa[1][jd]);
    }
  __builtin_amdgcn_s_setprio(0);

  #pragma unroll
  for (int iq=0;iq<2;++iq){
    #pragma unroll
    for (int jd=0;jd<4;++jd){
      int col = hh*64 + jd*16 + c;
      int pc = pcol32(col & ~31, jd&1, c>>2, c&3);
      #pragma unroll
      for (int r=0;r<4;++r){
        int m = m0 + w*32 + iq*16 + g*4 + r;
        o[(size_t)m*INNERD + pc] = f2bf(oa[iq][jd][r]);
      }
    }
  }
}

// ---------------------------------------------------------------------------
// Gated-FFN GEMM (K=256): a/g panels, act = a * gelu(g), permuted bf16 store.
// Simple 2-phase, 48KB LDS, (256,3): R8 measured occupancy 21->30% from the
// launch-bounds change alone (VGPR 104->84); retried here without the L3
// confound. Mechanism: wave-level overlap hides the 2-phase drain (m114).
// ---------------------------------------------------------------------------
__global__ __launch_bounds__(256, 3) void gemm_gated_kernel(
    const u16* __restrict__ A, const u16* __restrict__ Bt,
    u16* __restrict__ act, const float* __restrict__ b1, int K)
{
  __shared__ __align__(16) u16 As[128*64];
  __shared__ __align__(16) u16 Ba[128*64];
  __shared__ __align__(16) u16 Bg[128*64];
  const int t = threadIdx.x;
  const int w = t >> 6, lane = t & 63, g = lane >> 4, c = lane & 15;
  const int cpx = gridDim.x >> 3;
  const int wg = (blockIdx.x & 7)*cpx + (blockIdx.x >> 3);
  const int n0 = (wg & 7) * 128, m0 = (wg >> 3) * 128;
  const int wm = (w >> 1) * 64, wn = (w & 1) * 64;

  f32x4 acca[4][4], accg[4][4];
  #pragma unroll
  for (int i=0;i<4;++i)
    #pragma unroll
    for (int j=0;j<4;++j){ f32x4 z = {0.f,0.f,0.f,0.f}; acca[i][j] = z; accg[i][j] = z; }

  const int nkt = K >> 6;
  for (int kt = 0; kt < nkt; ++kt){
    #pragma unroll
    for (int i=0;i<4;++i){
      int cid = (i*4 + w)*64 + lane;
      int row = cid >> 3, qs = cid & 7;
      int col16 = ((qs ^ (row&7))<<3);
      gload16(A  + (size_t)(m0+row)*K      + (size_t)kt*64 + col16, As + (i*4+w)*512);
      gload16(Bt + (size_t)(n0+row)*K      + (size_t)kt*64 + col16, Ba + (i*4+w)*512);
      gload16(Bt + (size_t)(1024+n0+row)*K + (size_t)kt*64 + col16, Bg + (i*4+w)*512);
    }
    asm volatile("s_waitcnt vmcnt(0)" ::: "memory");
    __syncthreads();
    #pragma unroll
    for (int kk=0; kk<2; ++kk){
      s16x8 af[4];
      #pragma unroll
      for (int i=0;i<4;++i) af[i] = ldfrag(As, wm + i*16 + c, kk, g);
      #pragma unroll
      for (int j=0;j<4;++j){
        int row = wn + j*16 + c;
        s16x8 bfa = ldfrag(Ba, row, kk, g);
        s16x8 bfg = ldfrag(Bg, row, kk, g);
        #pragma unroll
        for (int i=0;i<4;++i){
          acca[i][j] = mfma16(af[i], bfa, acca[i][j]);
          accg[i][j] = mfma16(af[i], bfg, accg[i][j]);
        }
      }
    }
    __syncthreads();
  }

  #pragma unroll
  for (int i=0;i<4;++i)
    #pragma unroll
    for (int j=0;j<4;++j){
      int col = n0 + wn + j*16 + c;
      int pc = pcol32(col & ~31, j&1, c>>2, c&3);
      float ba = b1[col], bg = b1[1024 + col];
      #pragma unroll
      for (int r=0;r<4;++r){
        int m = m0 + wm + i*16 + g*4 + r;
        float ua = acca[i][j][r] + ba;
        float ug = accg[i][j][r] + bg;
        float gel = 0.5f*ug*(1.0f + erff(ug*0.70710678118654752f));
        act[(size_t)m*FFDIM + pc] = f2bf(ua*gel);
      }
    }
}

// ---------------------------------------------------------------------------
// Residual GEMM + LN fusion: tile 64 x 256 (full N), 4 waves, 42KB LDS ->
// 3 blocks/CU (R6 configuration, best measured). h += acc + bias; if DO_LN:
// n = LN(h)*gam+bet (permuted), pass 2 from registers.
// ---------------------------------------------------------------------------
template<int DO_LN>
__global__ __launch_bounds__(256, 3) void gemm_res_ln_kernel(
    const u16* __restrict__ A, const u16* __restrict__ Bt,
    float* __restrict__ h, const float* __restrict__ bias,
    const float* __restrict__ gam, const float* __restrict__ bet,
    u16* __restrict__ nout, int K)
{
  __shared__ __align__(16) u16 As[64*64];
  __shared__ __align__(16) u16 Bs[256*64];
  __shared__ float ps[64][4];
  const int t = threadIdx.x;
  const int w = t >> 6, lane = t & 63, g = lane >> 4, c = lane & 15;
  const int wr = w >> 1, wc = w & 1;
  const int m0 = blockIdx.x * 64;

  f32x4 acc[2][8];
  #pragma unroll
  for (int i=0;i<2;++i)
    #pragma unroll
    for (int j=0;j<8;++j){ f32x4 z = {0.f,0.f,0.f,0.f}; acc[i][j] = z; }

  const int nkt = K >> 6;
  for (int kt = 0; kt < nkt; ++kt){
    #pragma unroll
    for (int i=0;i<2;++i){            // A: 64 rows x 8 chunks
      int cid = i*256 + t;
      int row = cid >> 3, qs = cid & 7;
      gload16(A + (size_t)(m0+row)*K + (size_t)kt*64 + ((qs ^ (row&7))<<3),
              As + cid*8);
    }
    #pragma unroll
    for (int i=0;i<8;++i){            // B: 256 rows x 8 chunks
      int cid = (i*4 + w)*64 + lane;
      int row = cid >> 3, qs = cid & 7;
      gload16(Bt + (size_t)row*K + (size_t)kt*64 + ((qs ^ (row&7))<<3),
              Bs + (i*4+w)*512);
    }
    asm volatile("s_waitcnt vmcnt(0)" ::: "memory");
    __syncthreads();
    #pragma unroll
    for (int kk=0; kk<2; ++kk){
      s16x8 af[2];
      #pragma unroll
      for (int i=0;i<2;++i) af[i] = ldfrag(As, wr*32 + i*16 + c, kk, g);
      #pragma unroll
      for (int j=0;j<8;++j){
        s16x8 bf = ldfrag(Bs, wc*128 + j*16 + c, kk, g);
        #pragma unroll
        for (int i=0;i<2;++i) acc[i][j] = mfma16(af[i], bf, acc[i][j]);
      }
    }
    __syncthreads();
  }

  // pass 1: residual add, h store, updated value kept in acc, row sums -> LDS
  #pragma unroll
  for (int i=0;i<2;++i){
    #pragma unroll
    for (int r=0;r<4;++r){
      int rl = wr*32 + i*16 + g*4 + r;
      size_t mrow = (size_t)(m0 + rl)*DMODEL;
      float s = 0.f, q2 = 0.f;
      #pragma unroll
      for (int j=0;j<8;++j){
        int col = wc*128 + j*16 + c;
        float v = acc[i][j][r] + bias[col] + h[mrow + col];
        h[mrow + col] = v;
        acc[i][j][r] = v;
        s += v; q2 += v*v;
      }
      if (DO_LN){
        #pragma unroll
        for (int mask=1; mask<16; mask<<=1){
          s  += __shfl_xor(s,  mask);
          q2 += __shfl_xor(q2, mask);
        }
        if (c == 0){ ps[rl][wc*2] = s; ps[rl][wc*2+1] = q2; }
      }
    }
  }
  if (DO_LN){
    __syncthreads();
    #pragma unroll
    for (int i=0;i<2;++i){
      #pragma unroll
      for (int r=0;r<4;++r){
        int rl = wr*32 + i*16 + g*4 + r;
        size_t mrow = (size_t)(m0 + rl)*DMODEL;
        float st = ps[rl][0] + ps[rl][2];
        float qt = ps[rl][1] + ps[rl][3];
        float mean = st*(1.f/256.f);
        float var  = qt*(1.f/256.f) - mean*mean;
        float rs   = rsqrtf(var + 1e-5f);
        #pragma unroll
        for (int j=0;j<8;++j){
          int col = wc*128 + j*16 + c;
          float v = acc[i][j][r];
          int pc = pcol32(col & ~31, j&1, c>>2, c&3);
          nout[mrow + pc] = f2bf((v-mean)*rs*gam[col] + bet[col]);
        }
      }
    }
  }
}

// ---------------------------------------------------------------------------
extern "C" void kernel_launch(void* const* d_in, const int* in_sizes, int n_in,
                              void* d_out, int out_size, void* d_ws, size_t ws_size,
                              hipStream_t stream)
{
  const int*   x    = (const int*)  d_in[0];
  const float* E    = (const float*)d_in[1];
  const float* ln1g = (const float*)d_in[2];
  const float* ln1b = (const float*)d_in[3];
  const float* Wqkv = (const float*)d_in[4];
  const float* Wout = (const float*)d_in[5];
  const float* bout = (const float*)d_in[6];
  const float* ln2g = (const float*)d_in[7];
  const float* ln2b = (const float*)d_in[8];
  const float* W1   = (const float*)d_in[9];
  const float* b1   = (const float*)d_in[10];
  const float* W2   = (const float*)d_in[11];
  const float* b2   = (const float*)d_in[12];
  float* h = (float*)d_out;

  const size_t WQKV = (size_t)LAYERS*1536*256;
  const size_t WOUT = (size_t)LAYERS*256*512;
  const size_t W1T  = (size_t)LAYERS*2048*256;
  const size_t W2T  = (size_t)LAYERS*256*1024;
  u16* wqkv_t = (u16*)d_ws;
  u16* wout_t = wqkv_t + WQKV;
  u16* w1_t   = wout_t + WOUT;
  u16* w2_t   = w1_t   + W1T;
  u16* abase  = w2_t   + W2T;
  const size_t wbytes = (WQKV + WOUT + W1T + W2T) * 2;
  if (ws_size < wbytes + (size_t)1024*3584) return;
  size_t rem = ws_size - wbytes;

  // per-token activation bytes: n(512) + o(1024) + act(2048) bf16 = 3584 B.
  // Mc=32768 -> live set ~150MB, L3-safe.
  int Mc = MCAP;
  while (Mc > 1024 && (size_t)Mc*3584 > rem) Mc >>= 1;
  const int nc = MTOK / Mc;

  u16* n_bf   = abase;                       // [Mc][256]  permuted
  u16* o_bf   = n_bf + (size_t)Mc*256;       // [Mc][512]  permuted
  u16* act_bf = o_bf + (size_t)Mc*512;       // [Mc][1024] permuted

  int tot;
  tot = LAYERS*1536*256; wtrans_kernel<<<(tot+255)/256,256,0,stream>>>(Wqkv, wqkv_t, 256,  1536, tot);
  tot = LAYERS*256*512;  wtrans_kernel<<<(tot+255)/256,256,0,stream>>>(Wout, wout_t, 512,  256,  tot);
  tot = LAYERS*2048*256; wtrans_kernel<<<(tot+255)/256,256,0,stream>>>(W1,   w1_t,   256,  2048, tot);
  tot = LAYERS*256*1024; wtrans_kernel<<<(tot+255)/256,256,0,stream>>>(W2,   w2_t,   1024, 256,  tot);

  for (int cidx=0; cidx<nc; ++cidx){
    float* hc = h + (size_t)cidx*Mc*256;
    const int* xc = x + (size_t)cidx*Mc;
    embed_ln_kernel<<<Mc/4,256,0,stream>>>(xc, E, ln1g, ln1b, hc, n_bf);
    for (int l=0; l<LAYERS; ++l){
      qkv_attn_kernel<<<8*(Mc/128),256,0,stream>>>(
          n_bf, wqkv_t + (size_t)l*1536*256, o_bf, 256);
      gemm_res_ln_kernel<1><<<Mc/64,256,0,stream>>>(
          o_bf, wout_t + (size_t)l*256*512, hc, bout + l*256,
          ln2g + l*256, ln2b + l*256, n_bf, 512);
      gemm_gated_kernel<<<8*(Mc/128),256,0,stream>>>(
          n_bf, w1_t + (size_t)l*2048*256, act_bf, b1 + l*2048, 256);
      if (l < LAYERS-1){
        gemm_res_ln_kernel<1><<<Mc/64,256,0,stream>>>(
            act_bf, w2_t + (size_t)l*256*1024, hc, b2 + l*256,
            ln1g + (l+1)*256, ln1b + (l+1)*256, n_bf, 1024);
      } else {
        gemm_res_ln_kernel<0><<<Mc/64,256,0,stream>>>(
            act_bf, w2_t + (size_t)l*256*1024, hc, b2 + l*256,
            nullptr, nullptr, nullptr, 1024);
      }
    }
  }
}

// Round 11
// 3911.078 us; speedup vs baseline: 1.1506x; 1.1506x over previous
//
#include <hip/hip_runtime.h>
#include <stdint.h>
#include <math.h>

// ---------------------------------------------------------------------------
// Transformer forward, MI355X. bf16 MFMA operands, fp32 accum, fp32 residual.
// GEMM: C[M,N] = A[M,K] x Bt[N,K]^T, both K-major bf16.
// K-dim of all GEMM inputs stored PERMUTED within each 32-block:
//   k = 32*kk + 16*hi + 4*g + o  ->  p = 32*kk + 8*g + 4*hi + o
// so one MFMA fragment = one contiguous 16B chunk -> single ds_read_b128.
// Chunks XOR-swizzled by row&7 (pre-swizzled global source; linear LDS dest).
// qkv_attn: swapped QK^T (S^T = K@Q^T) -> P stays in registers; V-epilogue
// packs 4 consecutive key-slots into one ds_write_b64.
// OCCUPANCY LESSON (R8/R10): gated at (256,3) raises concurrency -> live
// tile footprint exceeds cache equilibrium -> FETCH 20->43MB, dur +50%.
// Keep gated at (256,2). Mc=32768 keeps live set ~150MB < 256MB L3 (R4/R8).
// ---------------------------------------------------------------------------

#define LAYERS 6
#define BATCH  2048
#define SEQ    64
#define DMODEL 256
#define NHEAD  8
#define INNERD 512
#define FFDIM  1024
#define VOCAB  100
#define MTOK   (BATCH*SEQ)
#define MCAP   32768

typedef unsigned short u16;
typedef __attribute__((ext_vector_type(4))) float f32x4;
typedef __attribute__((ext_vector_type(4))) short s16x4;
typedef __attribute__((ext_vector_type(8))) short s16x8;

__device__ inline u16 f2bf(float f){
  union { float f; unsigned int u; } x; x.f = f;
  unsigned int u = x.u;
  return (u16)((u + 0x7fffu + ((u >> 16) & 1u)) >> 16);
}

__device__ inline void gload16(const void* g, void* l){
  __builtin_amdgcn_global_load_lds(
      (const __attribute__((address_space(1))) unsigned int*)g,
      (__attribute__((address_space(3))) unsigned int*)l, 16, 0, 0);
}

__device__ inline f32x4 mfma16(s16x8 a, s16x8 b, f32x4 c){
  return __builtin_amdgcn_mfma_f32_16x16x32_bf16(a, b, c, 0, 0, 0);
}

// fragment = one 16B chunk (permuted layout), single ds_read_b128
__device__ inline s16x8 ldfrag(const u16* lds, int row, int kk, int g){
  int chunk = ((kk<<2)|g) ^ (row&7);
  return *(const s16x8*)(lds + row*64 + chunk*8);
}

// permuted column index for within-32-block k remap (writers)
__device__ inline int pcol32(int col_base32, int hi, int g, int o){
  return col_base32 | (g<<3) | (hi<<2) | o;
}

// ---------------------------------------------------------------------------
// weight convert+transpose+permute: out[l][n][p(k)] = bf16(in[l][k][n])
// ---------------------------------------------------------------------------
__global__ __launch_bounds__(256) void wtrans_kernel(
    const float* __restrict__ in, u16* __restrict__ out, int K, int N, int total)
{
  int idx = blockIdx.x*256 + threadIdx.x;
  if (idx >= total) return;
  int l = idx / (N*K);
  int r = idx - l*(N*K);
  int n = r / K;
  int k = r - n*K;
  int p = (k & ~31) | (((k>>2)&3)<<3) | (((k>>4)&1)<<2) | (k&3);
  out[(size_t)l*N*K + (size_t)n*K + p] = f2bf(in[(size_t)l*K*N + (size_t)k*N + n]);
}

// ---------------------------------------------------------------------------
// embed + ln1[0]: h = E-gather (fp32), n = LN(h) (bf16, permuted)
// ---------------------------------------------------------------------------
__global__ __launch_bounds__(256) void embed_ln_kernel(
    const int* __restrict__ x, const float* __restrict__ E,
    const float* __restrict__ gam, const float* __restrict__ bet,
    float* __restrict__ h, u16* __restrict__ nout)
{
  int t = threadIdx.x;
  int m = blockIdx.x*4 + (t>>6);
  int lane = t & 63;
  int s = m & 63;
  int tok = x[m];
  const float4 v = *(const float4*)(E + ((size_t)s*VOCAB + tok)*DMODEL + lane*4);
  *(float4*)(h + (size_t)m*DMODEL + lane*4) = v;
  float su = v.x+v.y+v.z+v.w;
  float q  = v.x*v.x+v.y*v.y+v.z*v.z+v.w*v.w;
  #pragma unroll
  for (int mask=1; mask<64; mask<<=1){
    su += __shfl_xor(su, mask);
    q  += __shfl_xor(q,  mask);
  }
  float mean = su*(1.f/256.f);
  float var  = q*(1.f/256.f) - mean*mean;
  float rs   = rsqrtf(var + 1e-5f);
  const float4 gv = *(const float4*)(gam + lane*4);
  const float4 bv = *(const float4*)(bet + lane*4);
  ushort4 ov;
  ov.x = f2bf((v.x-mean)*rs*gv.x + bv.x);
  ov.y = f2bf((v.y-mean)*rs*gv.y + bv.y);
  ov.z = f2bf((v.z-mean)*rs*gv.z + bv.z);
  ov.w = f2bf((v.w-mean)*rs*gv.w + bv.w);
  int p4 = (lane>>3)*32 + (lane&3)*8 + ((lane>>2)&1)*4;   // permuted base
  *(ushort4*)(nout + (size_t)m*DMODEL + p4) = ov;
}

// ---------------------------------------------------------------------------
// FUSED QKV GEMM + attention. Block = 128 tokens (2 seqs) x 1 head, 4 waves.
// setprio(1) wraps MFMA clusters. V-epilogue: one ds_write_b64 per (i,j).
// ---------------------------------------------------------------------------
__global__ __launch_bounds__(256, 3) void qkv_attn_kernel(
    const u16* __restrict__ A, const u16* __restrict__ Bt,
    u16* __restrict__ o, int K)
{
  __shared__ __align__(16) u16 smem[24576];   // 49152 B
  u16* As = smem;            // [128][64] GEMM staging
  u16* Bs = smem + 8192;     // [192][64] GEMM staging
  u16* qs = smem;            // [128 tok][64 d]   permuted chunks, overlays As
  u16* ks = smem + 8192;     // [128 tok][64 d]   overlays Bs
  u16* vt = smem + 16384;    // [seq*64+d][64 key] permuted chunks

  const int t = threadIdx.x;
  const int w = t >> 6, lane = t & 63, g = lane >> 4, c = lane & 15;
  const int cpx = gridDim.x >> 3;
  const int wg = (blockIdx.x & 7)*cpx + (blockIdx.x >> 3);
  const int hh = wg & 7;
  const int m0 = (wg >> 3) * 128;

  // ---- phase 1: GEMM. wave = 32-row strip x 192 cols. acc[2][12].
  f32x4 acc[2][12];
  #pragma unroll
  for (int i=0;i<2;++i)
    #pragma unroll
    for (int j=0;j<12;++j){ f32x4 z = {0.f,0.f,0.f,0.f}; acc[i][j] = z; }

  const int nkt = K >> 6;   // 4
  for (int kt = 0; kt < nkt; ++kt){
    #pragma unroll
    for (int i=0;i<4;++i){   // A: 128 rows x 8 chunks
      int cid = (i*4 + w)*64 + lane;
      int row = cid >> 3, seg = cid & 7;
      gload16(A + (size_t)(m0+row)*K + (size_t)kt*64 + ((seg ^ (row&7))<<3),
              As + cid*8);
    }
    #pragma unroll
    for (int i=0;i<6;++i){   // B: 192 rows (q|k|v of head hh) x 8 chunks
      int cid = (i*4 + w)*64 + lane;
      int brow = cid >> 3, seg = cid & 7;
      int ng = (brow>>6)*512 + hh*64 + (brow & 63);
      gload16(Bt + (size_t)ng*K + (size_t)kt*64 + ((seg ^ (brow&7))<<3),
              Bs + cid*8);
    }
    asm volatile("s_waitcnt vmcnt(0)" ::: "memory");
    __syncthreads();
    __builtin_amdgcn_s_setprio(1);
    #pragma unroll
    for (int kk=0; kk<2; ++kk){
      s16x8 af[2];
      #pragma unroll
      for (int i=0;i<2;++i) af[i] = ldfrag(As, w*32 + i*16 + c, kk, g);
      #pragma unroll
      for (int j=0;j<12;++j){
        s16x8 bf = ldfrag(Bs, j*16 + c, kk, g);
        acc[0][j] = mfma16(af[0], bf, acc[0][j]);
        acc[1][j] = mfma16(af[1], bf, acc[1][j]);
      }
    }
    __builtin_amdgcn_s_setprio(0);
    __syncthreads();
  }

  // ---- epilogue: quantize, scatter into permuted+XOR q/k/v LDS tiles
  // q/k: scalar (rows differ per r). V: r=0..3 -> 4 consecutive key slots
  //      (pos = hi*4 + r within chunk) -> one b64 write.
  #pragma unroll
  for (int i=0;i<2;++i){
    #pragma unroll
    for (int j=0;j<8;++j){
      #pragma unroll
      for (int r=0;r<4;++r){
        int tl = w*32 + i*16 + g*4 + r;
        u16 val = f2bf(acc[i][j][r]);
        int chunk = ((j&3)>>1)*4 + (c>>2);
        int pos   = (j&1)*4 + (c&3);
        u16* base = (j < 4) ? qs : ks;
        base[tl*64 + ((chunk ^ (tl&7))<<3) + pos] = val;
      }
    }
    #pragma unroll
    for (int j=8;j<12;++j){
      int tlb = w*32 + i*16 + g*4;          // token base, = 0 mod 4
      int d = (j-8)*16 + c;
      int row = (tlb & 64) + d;
      int kb = tlb & 63;
      int chunk = ((kb>>5)<<2) | ((kb>>2)&3);
      int hi = (kb>>4)&1;
      union { s16x4 v; u16 e[4]; } u;
      #pragma unroll
      for (int r=0;r<4;++r) u.e[r] = f2bf(acc[i][j][r]);
      *(s16x4*)(vt + row*64 + ((chunk ^ (row&7))<<3) + hi*4) = u.v;
    }
  }
  __syncthreads();

  // ---- phase 2: attention (32 queries/wave, seq = w>>1)
  const int seq = w >> 1;
  const int qrow = w*32;

  // S^T = K @ Q^T : sc[jk][iq], lane (g,c) holds keys jk*16+4g+{0..3}
  // for query iq*16+c.
  f32x4 sc[4][2];
  #pragma unroll
  for (int jk=0;jk<4;++jk){ f32x4 z = {0.f,0.f,0.f,0.f}; sc[jk][0]=z; sc[jk][1]=z; }
  __builtin_amdgcn_s_setprio(1);
  #pragma unroll
  for (int kk=0;kk<2;++kk){
    s16x8 qf0 = ldfrag(qs, qrow + c,      kk, g);
    s16x8 qf1 = ldfrag(qs, qrow + 16 + c, kk, g);
    #pragma unroll
    for (int jk=0;jk<4;++jk){
      s16x8 kf = ldfrag(ks, seq*64 + jk*16 + c, kk, g);
      sc[jk][0] = mfma16(kf, qf0, sc[jk][0]);
      sc[jk][1] = mfma16(kf, qf1, sc[jk][1]);
    }
  }
  __builtin_amdgcn_s_setprio(0);

  // softmax fully in registers; P packs directly into PV A-fragments
  s16x8 af[2][2];
  #pragma unroll
  for (int iq=0;iq<2;++iq){
    float mx = sc[0][iq][0];
    #pragma unroll
    for (int jk=0;jk<4;++jk)
      #pragma unroll
      for (int r=0;r<4;++r) mx = fmaxf(mx, sc[jk][iq][r]);
    mx = fmaxf(mx, __shfl_xor(mx, 16));
    mx = fmaxf(mx, __shfl_xor(mx, 32));
    float p[4][4];
    float sm = 0.f;
    #pragma unroll
    for (int jk=0;jk<4;++jk)
      #pragma unroll
      for (int r=0;r<4;++r){
        float e = expf((sc[jk][iq][r]-mx)*0.125f);
        p[jk][r] = e; sm += e;
      }
    sm += __shfl_xor(sm, 16);
    sm += __shfl_xor(sm, 32);
    float inv = 1.f/sm;
    #pragma unroll
    for (int kk=0;kk<2;++kk){
      union { s16x8 v; u16 e[8]; } u;
      #pragma unroll
      for (int oo=0;oo<4;++oo){
        u.e[oo]   = f2bf(p[2*kk  ][oo]*inv);   // key 32kk+4g+oo
        u.e[4+oo] = f2bf(p[2*kk+1][oo]*inv);   // key 32kk+16+4g+oo
      }
      af[iq][kk] = u.v;
    }
  }

  // O = P @ V
  f32x4 oa[2][4];
  #pragma unroll
  for (int jd=0;jd<4;++jd){ f32x4 z = {0.f,0.f,0.f,0.f}; oa[0][jd]=z; oa[1][jd]=z; }
  __builtin_amdgcn_s_setprio(1);
  #pragma unroll
  for (int kk=0;kk<2;++kk)
    #pragma unroll
    for (int jd=0;jd<4;++jd){
      s16x8 vf = ldfrag(vt, seq*64 + jd*16 + c, kk, g);
      oa[0][jd] = mfma16(af[0][kk], vf, oa[0][jd]);
      oa[1][jd] = mfma16(af[1][kk], vf, oa[1][jd]);
    }
  __builtin_amdgcn_s_setprio(0);

  #pragma unroll
  for (int iq=0;iq<2;++iq){
    #pragma unroll
    for (int jd=0;jd<4;++jd){
      int col = hh*64 + jd*16 + c;
      int pc = pcol32(col & ~31, jd&1, c>>2, c&3);
      #pragma unroll
      for (int r=0;r<4;++r){
        int m = m0 + w*32 + iq*16 + g*4 + r;
        o[(size_t)m*INNERD + pc] = f2bf(oa[iq][jd][r]);
      }
    }
  }
}

// ---------------------------------------------------------------------------
// Gated-FFN GEMM (K=256): a/g panels, act = a * gelu(g), permuted bf16 store.
// Simple 2-phase, 48KB LDS, (256,2). DO NOT raise to (256,3): measured twice
// (R8 confounded, R10 clean) -- extra concurrency doubles FETCH (cache
// footprint growth) and costs +50% dur.
// ---------------------------------------------------------------------------
__global__ __launch_bounds__(256, 2) void gemm_gated_kernel(
    const u16* __restrict__ A, const u16* __restrict__ Bt,
    u16* __restrict__ act, const float* __restrict__ b1, int K)
{
  __shared__ __align__(16) u16 As[128*64];
  __shared__ __align__(16) u16 Ba[128*64];
  __shared__ __align__(16) u16 Bg[128*64];
  const int t = threadIdx.x;
  const int w = t >> 6, lane = t & 63, g = lane >> 4, c = lane & 15;
  const int cpx = gridDim.x >> 3;
  const int wg = (blockIdx.x & 7)*cpx + (blockIdx.x >> 3);
  const int n0 = (wg & 7) * 128, m0 = (wg >> 3) * 128;
  const int wm = (w >> 1) * 64, wn = (w & 1) * 64;

  f32x4 acca[4][4], accg[4][4];
  #pragma unroll
  for (int i=0;i<4;++i)
    #pragma unroll
    for (int j=0;j<4;++j){ f32x4 z = {0.f,0.f,0.f,0.f}; acca[i][j] = z; accg[i][j] = z; }

  const int nkt = K >> 6;
  for (int kt = 0; kt < nkt; ++kt){
    #pragma unroll
    for (int i=0;i<4;++i){
      int cid = (i*4 + w)*64 + lane;
      int row = cid >> 3, qs = cid & 7;
      int col16 = ((qs ^ (row&7))<<3);
      gload16(A  + (size_t)(m0+row)*K      + (size_t)kt*64 + col16, As + (i*4+w)*512);
      gload16(Bt + (size_t)(n0+row)*K      + (size_t)kt*64 + col16, Ba + (i*4+w)*512);
      gload16(Bt + (size_t)(1024+n0+row)*K + (size_t)kt*64 + col16, Bg + (i*4+w)*512);
    }
    asm volatile("s_waitcnt vmcnt(0)" ::: "memory");
    __syncthreads();
    #pragma unroll
    for (int kk=0; kk<2; ++kk){
      s16x8 af[4];
      #pragma unroll
      for (int i=0;i<4;++i) af[i] = ldfrag(As, wm + i*16 + c, kk, g);
      #pragma unroll
      for (int j=0;j<4;++j){
        int row = wn + j*16 + c;
        s16x8 bfa = ldfrag(Ba, row, kk, g);
        s16x8 bfg = ldfrag(Bg, row, kk, g);
        #pragma unroll
        for (int i=0;i<4;++i){
          acca[i][j] = mfma16(af[i], bfa, acca[i][j]);
          accg[i][j] = mfma16(af[i], bfg, accg[i][j]);
        }
      }
    }
    __syncthreads();
  }

  #pragma unroll
  for (int i=0;i<4;++i)
    #pragma unroll
    for (int j=0;j<4;++j){
      int col = n0 + wn + j*16 + c;
      int pc = pcol32(col & ~31, j&1, c>>2, c&3);
      float ba = b1[col], bg = b1[1024 + col];
      #pragma unroll
      for (int r=0;r<4;++r){
        int m = m0 + wm + i*16 + g*4 + r;
        float ua = acca[i][j][r] + ba;
        float ug = accg[i][j][r] + bg;
        float gel = 0.5f*ug*(1.0f + erff(ug*0.70710678118654752f));
        act[(size_t)m*FFDIM + pc] = f2bf(ua*gel);
      }
    }
}

// ---------------------------------------------------------------------------
// Residual GEMM + LN fusion: tile 64 x 256 (full N), 4 waves, 42KB LDS ->
// 3 blocks/CU (R6 configuration, best measured). h += acc + bias; if DO_LN:
// n = LN(h)*gam+bet (permuted), pass 2 from registers.
// ---------------------------------------------------------------------------
template<int DO_LN>
__global__ __launch_bounds__(256, 3) void gemm_res_ln_kernel(
    const u16* __restrict__ A, const u16* __restrict__ Bt,
    float* __restrict__ h, const float* __restrict__ bias,
    const float* __restrict__ gam, const float* __restrict__ bet,
    u16* __restrict__ nout, int K)
{
  __shared__ __align__(16) u16 As[64*64];
  __shared__ __align__(16) u16 Bs[256*64];
  __shared__ float ps[64][4];
  const int t = threadIdx.x;
  const int w = t >> 6, lane = t & 63, g = lane >> 4, c = lane & 15;
  const int wr = w >> 1, wc = w & 1;
  const int m0 = blockIdx.x * 64;

  f32x4 acc[2][8];
  #pragma unroll
  for (int i=0;i<2;++i)
    #pragma unroll
    for (int j=0;j<8;++j){ f32x4 z = {0.f,0.f,0.f,0.f}; acc[i][j] = z; }

  const int nkt = K >> 6;
  for (int kt = 0; kt < nkt; ++kt){
    #pragma unroll
    for (int i=0;i<2;++i){            // A: 64 rows x 8 chunks
      int cid = i*256 + t;
      int row = cid >> 3, qs = cid & 7;
      gload16(A + (size_t)(m0+row)*K + (size_t)kt*64 + ((qs ^ (row&7))<<3),
              As + cid*8);
    }
    #pragma unroll
    for (int i=0;i<8;++i){            // B: 256 rows x 8 chunks
      int cid = (i*4 + w)*64 + lane;
      int row = cid >> 3, qs = cid & 7;
      gload16(Bt + (size_t)row*K + (size_t)kt*64 + ((qs ^ (row&7))<<3),
              Bs + (i*4+w)*512);
    }
    asm volatile("s_waitcnt vmcnt(0)" ::: "memory");
    __syncthreads();
    #pragma unroll
    for (int kk=0; kk<2; ++kk){
      s16x8 af[2];
      #pragma unroll
      for (int i=0;i<2;++i) af[i] = ldfrag(As, wr*32 + i*16 + c, kk, g);
      #pragma unroll
      for (int j=0;j<8;++j){
        s16x8 bf = ldfrag(Bs, wc*128 + j*16 + c, kk, g);
        #pragma unroll
        for (int i=0;i<2;++i) acc[i][j] = mfma16(af[i], bf, acc[i][j]);
      }
    }
    __syncthreads();
  }

  // pass 1: residual add, h store, updated value kept in acc, row sums -> LDS
  #pragma unroll
  for (int i=0;i<2;++i){
    #pragma unroll
    for (int r=0;r<4;++r){
      int rl = wr*32 + i*16 + g*4 + r;
      size_t mrow = (size_t)(m0 + rl)*DMODEL;
      float s = 0.f, q2 = 0.f;
      #pragma unroll
      for (int j=0;j<8;++j){
        int col = wc*128 + j*16 + c;
        float v = acc[i][j][r] + bias[col] + h[mrow + col];
        h[mrow + col] = v;
        acc[i][j][r] = v;
        s += v; q2 += v*v;
      }
      if (DO_LN){
        #pragma unroll
        for (int mask=1; mask<16; mask<<=1){
          s  += __shfl_xor(s,  mask);
          q2 += __shfl_xor(q2, mask);
        }
        if (c == 0){ ps[rl][wc*2] = s; ps[rl][wc*2+1] = q2; }
      }
    }
  }
  if (DO_LN){
    __syncthreads();
    #pragma unroll
    for (int i=0;i<2;++i){
      #pragma unroll
      for (int r=0;r<4;++r){
        int rl = wr*32 + i*16 + g*4 + r;
        size_t mrow = (size_t)(m0 + rl)*DMODEL;
        float st = ps[rl][0] + ps[rl][2];
        float qt = ps[rl][1] + ps[rl][3];
        float mean = st*(1.f/256.f);
        float var  = qt*(1.f/256.f) - mean*mean;
        float rs   = rsqrtf(var + 1e-5f);
        #pragma unroll
        for (int j=0;j<8;++j){
          int col = wc*128 + j*16 + c;
          float v = acc[i][j][r];
          int pc = pcol32(col & ~31, j&1, c>>2, c&3);
          nout[mrow + pc] = f2bf((v-mean)*rs*gam[col] + bet[col]);
        }
      }
    }
  }
}

// ---------------------------------------------------------------------------
extern "C" void kernel_launch(void* const* d_in, const int* in_sizes, int n_in,
                              void* d_out, int out_size, void* d_ws, size_t ws_size,
                              hipStream_t stream)
{
  const int*   x    = (const int*)  d_in[0];
  const float* E    = (const float*)d_in[1];
  const float* ln1g = (const float*)d_in[2];
  const float* ln1b = (const float*)d_in[3];
  const float* Wqkv = (const float*)d_in[4];
  const float* Wout = (const float*)d_in[5];
  const float* bout = (const float*)d_in[6];
  const float* ln2g = (const float*)d_in[7];
  const float* ln2b = (const float*)d_in[8];
  const float* W1   = (const float*)d_in[9];
  const float* b1   = (const float*)d_in[10];
  const float* W2   = (const float*)d_in[11];
  const float* b2   = (const float*)d_in[12];
  float* h = (float*)d_out;

  const size_t WQKV = (size_t)LAYERS*1536*256;
  const size_t WOUT = (size_t)LAYERS*256*512;
  const size_t W1T  = (size_t)LAYERS*2048*256;
  const size_t W2T  = (size_t)LAYERS*256*1024;
  u16* wqkv_t = (u16*)d_ws;
  u16* wout_t = wqkv_t + WQKV;
  u16* w1_t   = wout_t + WOUT;
  u16* w2_t   = w1_t   + W1T;
  u16* abase  = w2_t   + W2T;
  const size_t wbytes = (WQKV + WOUT + W1T + W2T) * 2;
  if (ws_size < wbytes + (size_t)1024*3584) return;
  size_t rem = ws_size - wbytes;

  // per-token activation bytes: n(512) + o(1024) + act(2048) bf16 = 3584 B.
  // Mc=32768 -> live set ~150MB, L3-safe.
  int Mc = MCAP;
  while (Mc > 1024 && (size_t)Mc*3584 > rem) Mc >>= 1;
  const int nc = MTOK / Mc;

  u16* n_bf   = abase;                       // [Mc][256]  permuted
  u16* o_bf   = n_bf + (size_t)Mc*256;       // [Mc][512]  permuted
  u16* act_bf = o_bf + (size_t)Mc*512;       // [Mc][1024] permuted

  int tot;
  tot = LAYERS*1536*256; wtrans_kernel<<<(tot+255)/256,256,0,stream>>>(Wqkv, wqkv_t, 256,  1536, tot);
  tot = LAYERS*256*512;  wtrans_kernel<<<(tot+255)/256,256,0,stream>>>(Wout, wout_t, 512,  256,  tot);
  tot = LAYERS*2048*256; wtrans_kernel<<<(tot+255)/256,256,0,stream>>>(W1,   w1_t,   256,  2048, tot);
  tot = LAYERS*256*1024; wtrans_kernel<<<(tot+255)/256,256,0,stream>>>(W2,   w2_t,   1024, 256,  tot);

  for (int cidx=0; cidx<nc; ++cidx){
    float* hc = h + (size_t)cidx*Mc*256;
    const int* xc = x + (size_t)cidx*Mc;
    embed_ln_kernel<<<Mc/4,256,0,stream>>>(xc, E, ln1g, ln1b, hc, n_bf);
    for (int l=0; l<LAYERS; ++l){
      qkv_attn_kernel<<<8*(Mc/128),256,0,stream>>>(
          n_bf, wqkv_t + (size_t)l*1536*256, o_bf, 256);
      gemm_res_ln_kernel<1><<<Mc/64,256,0,stream>>>(
          o_bf, wout_t + (size_t)l*256*512, hc, bout + l*256,
          ln2g + l*256, ln2b + l*256, n_bf, 512);
      gemm_gated_kernel<<<8*(Mc/128),256,0,stream>>>(
          n_bf, w1_t + (size_t)l*2048*256, act_bf, b1 + l*2048, 256);
      if (l < LAYERS-1){
        gemm_res_ln_kernel<1><<<Mc/64,256,0,stream>>>(
            act_bf, w2_t + (size_t)l*256*1024, hc, b2 + l*256,
            ln1g + (l+1)*256, ln1b + (l+1)*256, n_bf, 1024);
      } else {
        gemm_res_ln_kernel<0><<<Mc/64,256,0,stream>>>(
            act_bf, w2_t + (size_t)l*256*1024, hc, b2 + l*256,
            nullptr, nullptr, nullptr, 1024);
      }
    }
  }
}

// Round 12
// 3641.639 us; speedup vs baseline: 1.2357x; 1.0740x over previous
//
#include <hip/hip_runtime.h>
#include <stdint.h>
#include <math.h>

// ---------------------------------------------------------------------------
// Transformer forward, MI355X. bf16 MFMA operands, fp32 accum, fp32 residual.
// GEMM: C[M,N] = A[M,K] x Bt[N,K]^T, both K-major bf16.
// K-dim of all GEMM inputs stored PERMUTED within each 32-block:
//   k = 32*kk + 16*hi + 4*g + o  ->  p = 32*kk + 8*g + 4*hi + o
// so one MFMA fragment = one contiguous 16B chunk -> single ds_read_b128.
// Chunks XOR-swizzled by row&7 (pre-swizzled global source; linear LDS dest).
// qkv_attn: swapped QK^T (S^T = K@Q^T) -> P stays in registers.
// R12: VALU-side fix -- gated epilogue was 64 libm erff/thread (~2x the MFMA
// cycles; VALUBusy 46 vs MfmaUtil 24). Replaced with sigmoid-form fast GELU
// (__expf + rcp, ~8 ops); fast expf/rcp/rsq in softmax and LN.
// OCCUPANCY LESSON (R8/R10): gated stays (256,2) -- (256,3) doubles FETCH.
// Mc=32768 keeps live set ~150MB < 256MB L3 (R4/R8 lessons).
// ---------------------------------------------------------------------------

#define LAYERS 6
#define BATCH  2048
#define SEQ    64
#define DMODEL 256
#define NHEAD  8
#define INNERD 512
#define FFDIM  1024
#define VOCAB  100
#define MTOK   (BATCH*SEQ)
#define MCAP   32768

typedef unsigned short u16;
typedef __attribute__((ext_vector_type(4))) float f32x4;
typedef __attribute__((ext_vector_type(4))) short s16x4;
typedef __attribute__((ext_vector_type(8))) short s16x8;

__device__ inline u16 f2bf(float f){
  union { float f; unsigned int u; } x; x.f = f;
  unsigned int u = x.u;
  return (u16)((u + 0x7fffu + ((u >> 16) & 1u)) >> 16);
}

// sigmoid-form tanh-GELU: x * sigma(2*sqrt(2/pi)*(x+0.044715x^3)).
// |gelu_tanh - gelu_erf| <~ 1e-3; graceful at +-inf (exp->inf->rcp->0).
__device__ inline float gelu_fast(float x){
  float t = __expf(-1.5957691216f*(x + 0.044715f*x*x*x));
  return x * __builtin_amdgcn_rcpf(1.0f + t);
}

__device__ inline void gload16(const void* g, void* l){
  __builtin_amdgcn_global_load_lds(
      (const __attribute__((address_space(1))) unsigned int*)g,
      (__attribute__((address_space(3))) unsigned int*)l, 16, 0, 0);
}

__device__ inline f32x4 mfma16(s16x8 a, s16x8 b, f32x4 c){
  return __builtin_amdgcn_mfma_f32_16x16x32_bf16(a, b, c, 0, 0, 0);
}

// fragment = one 16B chunk (permuted layout), single ds_read_b128
__device__ inline s16x8 ldfrag(const u16* lds, int row, int kk, int g){
  int chunk = ((kk<<2)|g) ^ (row&7);
  return *(const s16x8*)(lds + row*64 + chunk*8);
}

// permuted column index for within-32-block k remap (writers)
__device__ inline int pcol32(int col_base32, int hi, int g, int o){
  return col_base32 | (g<<3) | (hi<<2) | o;
}

// ---------------------------------------------------------------------------
// weight convert+transpose+permute: out[l][n][p(k)] = bf16(in[l][k][n])
// ---------------------------------------------------------------------------
__global__ __launch_bounds__(256) void wtrans_kernel(
    const float* __restrict__ in, u16* __restrict__ out, int K, int N, int total)
{
  int idx = blockIdx.x*256 + threadIdx.x;
  if (idx >= total) return;
  int l = idx / (N*K);
  int r = idx - l*(N*K);
  int n = r / K;
  int k = r - n*K;
  int p = (k & ~31) | (((k>>2)&3)<<3) | (((k>>4)&1)<<2) | (k&3);
  out[(size_t)l*N*K + (size_t)n*K + p] = f2bf(in[(size_t)l*K*N + (size_t)k*N + n]);
}

// ---------------------------------------------------------------------------
// embed + ln1[0]: h = E-gather (fp32), n = LN(h) (bf16, permuted)
// ---------------------------------------------------------------------------
__global__ __launch_bounds__(256) void embed_ln_kernel(
    const int* __restrict__ x, const float* __restrict__ E,
    const float* __restrict__ gam, const float* __restrict__ bet,
    float* __restrict__ h, u16* __restrict__ nout)
{
  int t = threadIdx.x;
  int m = blockIdx.x*4 + (t>>6);
  int lane = t & 63;
  int s = m & 63;
  int tok = x[m];
  const float4 v = *(const float4*)(E + ((size_t)s*VOCAB + tok)*DMODEL + lane*4);
  *(float4*)(h + (size_t)m*DMODEL + lane*4) = v;
  float su = v.x+v.y+v.z+v.w;
  float q  = v.x*v.x+v.y*v.y+v.z*v.z+v.w*v.w;
  #pragma unroll
  for (int mask=1; mask<64; mask<<=1){
    su += __shfl_xor(su, mask);
    q  += __shfl_xor(q,  mask);
  }
  float mean = su*(1.f/256.f);
  float var  = q*(1.f/256.f) - mean*mean;
  float rs   = __builtin_amdgcn_rsqf(var + 1e-5f);
  const float4 gv = *(const float4*)(gam + lane*4);
  const float4 bv = *(const float4*)(bet + lane*4);
  ushort4 ov;
  ov.x = f2bf((v.x-mean)*rs*gv.x + bv.x);
  ov.y = f2bf((v.y-mean)*rs*gv.y + bv.y);
  ov.z = f2bf((v.z-mean)*rs*gv.z + bv.z);
  ov.w = f2bf((v.w-mean)*rs*gv.w + bv.w);
  int p4 = (lane>>3)*32 + (lane&3)*8 + ((lane>>2)&1)*4;   // permuted base
  *(ushort4*)(nout + (size_t)m*DMODEL + p4) = ov;
}

// ---------------------------------------------------------------------------
// FUSED QKV GEMM + attention. Block = 128 tokens (2 seqs) x 1 head, 4 waves.
// setprio(1) wraps MFMA clusters. V-epilogue: one ds_write_b64 per (i,j).
// ---------------------------------------------------------------------------
__global__ __launch_bounds__(256, 3) void qkv_attn_kernel(
    const u16* __restrict__ A, const u16* __restrict__ Bt,
    u16* __restrict__ o, int K)
{
  __shared__ __align__(16) u16 smem[24576];   // 49152 B
  u16* As = smem;            // [128][64] GEMM staging
  u16* Bs = smem + 8192;     // [192][64] GEMM staging
  u16* qs = smem;            // [128 tok][64 d]   permuted chunks, overlays As
  u16* ks = smem + 8192;     // [128 tok][64 d]   overlays Bs
  u16* vt = smem + 16384;    // [seq*64+d][64 key] permuted chunks

  const int t = threadIdx.x;
  const int w = t >> 6, lane = t & 63, g = lane >> 4, c = lane & 15;
  const int cpx = gridDim.x >> 3;
  const int wg = (blockIdx.x & 7)*cpx + (blockIdx.x >> 3);
  const int hh = wg & 7;
  const int m0 = (wg >> 3) * 128;

  // ---- phase 1: GEMM. wave = 32-row strip x 192 cols. acc[2][12].
  f32x4 acc[2][12];
  #pragma unroll
  for (int i=0;i<2;++i)
    #pragma unroll
    for (int j=0;j<12;++j){ f32x4 z = {0.f,0.f,0.f,0.f}; acc[i][j] = z; }

  const int nkt = K >> 6;   // 4
  for (int kt = 0; kt < nkt; ++kt){
    #pragma unroll
    for (int i=0;i<4;++i){   // A: 128 rows x 8 chunks
      int cid = (i*4 + w)*64 + lane;
      int row = cid >> 3, seg = cid & 7;
      gload16(A + (size_t)(m0+row)*K + (size_t)kt*64 + ((seg ^ (row&7))<<3),
              As + cid*8);
    }
    #pragma unroll
    for (int i=0;i<6;++i){   // B: 192 rows (q|k|v of head hh) x 8 chunks
      int cid = (i*4 + w)*64 + lane;
      int brow = cid >> 3, seg = cid & 7;
      int ng = (brow>>6)*512 + hh*64 + (brow & 63);
      gload16(Bt + (size_t)ng*K + (size_t)kt*64 + ((seg ^ (brow&7))<<3),
              Bs + cid*8);
    }
    asm volatile("s_waitcnt vmcnt(0)" ::: "memory");
    __syncthreads();
    __builtin_amdgcn_s_setprio(1);
    #pragma unroll
    for (int kk=0; kk<2; ++kk){
      s16x8 af[2];
      #pragma unroll
      for (int i=0;i<2;++i) af[i] = ldfrag(As, w*32 + i*16 + c, kk, g);
      #pragma unroll
      for (int j=0;j<12;++j){
        s16x8 bf = ldfrag(Bs, j*16 + c, kk, g);
        acc[0][j] = mfma16(af[0], bf, acc[0][j]);
        acc[1][j] = mfma16(af[1], bf, acc[1][j]);
      }
    }
    __builtin_amdgcn_s_setprio(0);
    __syncthreads();
  }

  // ---- epilogue: quantize, scatter into permuted+XOR q/k/v LDS tiles
  #pragma unroll
  for (int i=0;i<2;++i){
    #pragma unroll
    for (int j=0;j<8;++j){
      #pragma unroll
      for (int r=0;r<4;++r){
        int tl = w*32 + i*16 + g*4 + r;
        u16 val = f2bf(acc[i][j][r]);
        int chunk = ((j&3)>>1)*4 + (c>>2);
        int pos   = (j&1)*4 + (c&3);
        u16* base = (j < 4) ? qs : ks;
        base[tl*64 + ((chunk ^ (tl&7))<<3) + pos] = val;
      }
    }
    #pragma unroll
    for (int j=8;j<12;++j){
      int tlb = w*32 + i*16 + g*4;          // token base, = 0 mod 4
      int d = (j-8)*16 + c;
      int row = (tlb & 64) + d;
      int kb = tlb & 63;
      int chunk = ((kb>>5)<<2) | ((kb>>2)&3);
      int hi = (kb>>4)&1;
      union { s16x4 v; u16 e[4]; } u;
      #pragma unroll
      for (int r=0;r<4;++r) u.e[r] = f2bf(acc[i][j][r]);
      *(s16x4*)(vt + row*64 + ((chunk ^ (row&7))<<3) + hi*4) = u.v;
    }
  }
  __syncthreads();

  // ---- phase 2: attention (32 queries/wave, seq = w>>1)
  const int seq = w >> 1;
  const int qrow = w*32;

  // S^T = K @ Q^T : sc[jk][iq], lane (g,c) holds keys jk*16+4g+{0..3}
  // for query iq*16+c.
  f32x4 sc[4][2];
  #pragma unroll
  for (int jk=0;jk<4;++jk){ f32x4 z = {0.f,0.f,0.f,0.f}; sc[jk][0]=z; sc[jk][1]=z; }
  __builtin_amdgcn_s_setprio(1);
  #pragma unroll
  for (int kk=0;kk<2;++kk){
    s16x8 qf0 = ldfrag(qs, qrow + c,      kk, g);
    s16x8 qf1 = ldfrag(qs, qrow + 16 + c, kk, g);
    #pragma unroll
    for (int jk=0;jk<4;++jk){
      s16x8 kf = ldfrag(ks, seq*64 + jk*16 + c, kk, g);
      sc[jk][0] = mfma16(kf, qf0, sc[jk][0]);
      sc[jk][1] = mfma16(kf, qf1, sc[jk][1]);
    }
  }
  __builtin_amdgcn_s_setprio(0);

  // softmax fully in registers; P packs directly into PV A-fragments
  s16x8 af[2][2];
  #pragma unroll
  for (int iq=0;iq<2;++iq){
    float mx = sc[0][iq][0];
    #pragma unroll
    for (int jk=0;jk<4;++jk)
      #pragma unroll
      for (int r=0;r<4;++r) mx = fmaxf(mx, sc[jk][iq][r]);
    mx = fmaxf(mx, __shfl_xor(mx, 16));
    mx = fmaxf(mx, __shfl_xor(mx, 32));
    float p[4][4];
    float sm = 0.f;
    #pragma unroll
    for (int jk=0;jk<4;++jk)
      #pragma unroll
      for (int r=0;r<4;++r){
        float e = __expf((sc[jk][iq][r]-mx)*0.125f);
        p[jk][r] = e; sm += e;
      }
    sm += __shfl_xor(sm, 16);
    sm += __shfl_xor(sm, 32);
    float inv = __builtin_amdgcn_rcpf(sm);
    #pragma unroll
    for (int kk=0;kk<2;++kk){
      union { s16x8 v; u16 e[8]; } u;
      #pragma unroll
      for (int oo=0;oo<4;++oo){
        u.e[oo]   = f2bf(p[2*kk  ][oo]*inv);   // key 32kk+4g+oo
        u.e[4+oo] = f2bf(p[2*kk+1][oo]*inv);   // key 32kk+16+4g+oo
      }
      af[iq][kk] = u.v;
    }
  }

  // O = P @ V
  f32x4 oa[2][4];
  #pragma unroll
  for (int jd=0;jd<4;++jd){ f32x4 z = {0.f,0.f,0.f,0.f}; oa[0][jd]=z; oa[1][jd]=z; }
  __builtin_amdgcn_s_setprio(1);
  #pragma unroll
  for (int kk=0;kk<2;++kk)
    #pragma unroll
    for (int jd=0;jd<4;++jd){
      s16x8 vf = ldfrag(vt, seq*64 + jd*16 + c, kk, g);
      oa[0][jd] = mfma16(af[0][kk], vf, oa[0][jd]);
      oa[1][jd] = mfma16(af[1][kk], vf, oa[1][jd]);
    }
  __builtin_amdgcn_s_setprio(0);

  #pragma unroll
  for (int iq=0;iq<2;++iq){
    #pragma unroll
    for (int jd=0;jd<4;++jd){
      int col = hh*64 + jd*16 + c;
      int pc = pcol32(col & ~31, jd&1, c>>2, c&3);
      #pragma unroll
      for (int r=0;r<4;++r){
        int m = m0 + w*32 + iq*16 + g*4 + r;
        o[(size_t)m*INNERD + pc] = f2bf(oa[iq][jd][r]);
      }
    }
  }
}

// ---------------------------------------------------------------------------
// Gated-FFN GEMM (K=256): a/g panels, act = a * gelu_fast(g), permuted store.
// Simple 2-phase, 48KB LDS, (256,2). DO NOT raise to (256,3): measured twice
// (R8 confounded, R10 clean) -- extra concurrency doubles FETCH.
// ---------------------------------------------------------------------------
__global__ __launch_bounds__(256, 2) void gemm_gated_kernel(
    const u16* __restrict__ A, const u16* __restrict__ Bt,
    u16* __restrict__ act, const float* __restrict__ b1, int K)
{
  __shared__ __align__(16) u16 As[128*64];
  __shared__ __align__(16) u16 Ba[128*64];
  __shared__ __align__(16) u16 Bg[128*64];
  const int t = threadIdx.x;
  const int w = t >> 6, lane = t & 63, g = lane >> 4, c = lane & 15;
  const int cpx = gridDim.x >> 3;
  const int wg = (blockIdx.x & 7)*cpx + (blockIdx.x >> 3);
  const int n0 = (wg & 7) * 128, m0 = (wg >> 3) * 128;
  const int wm = (w >> 1) * 64, wn = (w & 1) * 64;

  f32x4 acca[4][4], accg[4][4];
  #pragma unroll
  for (int i=0;i<4;++i)
    #pragma unroll
    for (int j=0;j<4;++j){ f32x4 z = {0.f,0.f,0.f,0.f}; acca[i][j] = z; accg[i][j] = z; }

  const int nkt = K >> 6;
  for (int kt = 0; kt < nkt; ++kt){
    #pragma unroll
    for (int i=0;i<4;++i){
      int cid = (i*4 + w)*64 + lane;
      int row = cid >> 3, qs = cid & 7;
      int col16 = ((qs ^ (row&7))<<3);
      gload16(A  + (size_t)(m0+row)*K      + (size_t)kt*64 + col16, As + (i*4+w)*512);
      gload16(Bt + (size_t)(n0+row)*K      + (size_t)kt*64 + col16, Ba + (i*4+w)*512);
      gload16(Bt + (size_t)(1024+n0+row)*K + (size_t)kt*64 + col16, Bg + (i*4+w)*512);
    }
    asm volatile("s_waitcnt vmcnt(0)" ::: "memory");
    __syncthreads();
    #pragma unroll
    for (int kk=0; kk<2; ++kk){
      s16x8 af[4];
      #pragma unroll
      for (int i=0;i<4;++i) af[i] = ldfrag(As, wm + i*16 + c, kk, g);
      #pragma unroll
      for (int j=0;j<4;++j){
        int row = wn + j*16 + c;
        s16x8 bfa = ldfrag(Ba, row, kk, g);
        s16x8 bfg = ldfrag(Bg, row, kk, g);
        #pragma unroll
        for (int i=0;i<4;++i){
          acca[i][j] = mfma16(af[i], bfa, acca[i][j]);
          accg[i][j] = mfma16(af[i], bfg, accg[i][j]);
        }
      }
    }
    __syncthreads();
  }

  #pragma unroll
  for (int i=0;i<4;++i)
    #pragma unroll
    for (int j=0;j<4;++j){
      int col = n0 + wn + j*16 + c;
      int pc = pcol32(col & ~31, j&1, c>>2, c&3);
      float ba = b1[col], bg = b1[1024 + col];
      #pragma unroll
      for (int r=0;r<4;++r){
        int m = m0 + wm + i*16 + g*4 + r;
        float ua = acca[i][j][r] + ba;
        float ug = accg[i][j][r] + bg;
        act[(size_t)m*FFDIM + pc] = f2bf(ua*gelu_fast(ug));
      }
    }
}

// ---------------------------------------------------------------------------
// Residual GEMM + LN fusion: tile 64 x 256 (full N), 4 waves, 42KB LDS ->
// 3 blocks/CU (R6 configuration, best measured). h += acc + bias; if DO_LN:
// n = LN(h)*gam+bet (permuted), pass 2 from registers.
// ---------------------------------------------------------------------------
template<int DO_LN>
__global__ __launch_bounds__(256, 3) void gemm_res_ln_kernel(
    const u16* __restrict__ A, const u16* __restrict__ Bt,
    float* __restrict__ h, const float* __restrict__ bias,
    const float* __restrict__ gam, const float* __restrict__ bet,
    u16* __restrict__ nout, int K)
{
  __shared__ __align__(16) u16 As[64*64];
  __shared__ __align__(16) u16 Bs[256*64];
  __shared__ float ps[64][4];
  const int t = threadIdx.x;
  const int w = t >> 6, lane = t & 63, g = lane >> 4, c = lane & 15;
  const int wr = w >> 1, wc = w & 1;
  const int m0 = blockIdx.x * 64;

  f32x4 acc[2][8];
  #pragma unroll
  for (int i=0;i<2;++i)
    #pragma unroll
    for (int j=0;j<8;++j){ f32x4 z = {0.f,0.f,0.f,0.f}; acc[i][j] = z; }

  const int nkt = K >> 6;
  for (int kt = 0; kt < nkt; ++kt){
    #pragma unroll
    for (int i=0;i<2;++i){            // A: 64 rows x 8 chunks
      int cid = i*256 + t;
      int row = cid >> 3, qs = cid & 7;
      gload16(A + (size_t)(m0+row)*K + (size_t)kt*64 + ((qs ^ (row&7))<<3),
              As + cid*8);
    }
    #pragma unroll
    for (int i=0;i<8;++i){            // B: 256 rows x 8 chunks
      int cid = (i*4 + w)*64 + lane;
      int row = cid >> 3, qs = cid & 7;
      gload16(Bt + (size_t)row*K + (size_t)kt*64 + ((qs ^ (row&7))<<3),
              Bs + (i*4+w)*512);
    }
    asm volatile("s_waitcnt vmcnt(0)" ::: "memory");
    __syncthreads();
    #pragma unroll
    for (int kk=0; kk<2; ++kk){
      s16x8 af[2];
      #pragma unroll
      for (int i=0;i<2;++i) af[i] = ldfrag(As, wr*32 + i*16 + c, kk, g);
      #pragma unroll
      for (int j=0;j<8;++j){
        s16x8 bf = ldfrag(Bs, wc*128 + j*16 + c, kk, g);
        #pragma unroll
        for (int i=0;i<2;++i) acc[i][j] = mfma16(af[i], bf, acc[i][j]);
      }
    }
    __syncthreads();
  }

  // pass 1: residual add, h store, updated value kept in acc, row sums -> LDS
  #pragma unroll
  for (int i=0;i<2;++i){
    #pragma unroll
    for (int r=0;r<4;++r){
      int rl = wr*32 + i*16 + g*4 + r;
      size_t mrow = (size_t)(m0 + rl)*DMODEL;
      float s = 0.f, q2 = 0.f;
      #pragma unroll
      for (int j=0;j<8;++j){
        int col = wc*128 + j*16 + c;
        float v = acc[i][j][r] + bias[col] + h[mrow + col];
        h[mrow + col] = v;
        acc[i][j][r] = v;
        s += v; q2 += v*v;
      }
      if (DO_LN){
        #pragma unroll
        for (int mask=1; mask<16; mask<<=1){
          s  += __shfl_xor(s,  mask);
          q2 += __shfl_xor(q2, mask);
        }
        if (c == 0){ ps[rl][wc*2] = s; ps[rl][wc*2+1] = q2; }
      }
    }
  }
  if (DO_LN){
    __syncthreads();
    #pragma unroll
    for (int i=0;i<2;++i){
      #pragma unroll
      for (int r=0;r<4;++r){
        int rl = wr*32 + i*16 + g*4 + r;
        size_t mrow = (size_t)(m0 + rl)*DMODEL;
        float st = ps[rl][0] + ps[rl][2];
        float qt = ps[rl][1] + ps[rl][3];
        float mean = st*(1.f/256.f);
        float var  = qt*(1.f/256.f) - mean*mean;
        float rs   = __builtin_amdgcn_rsqf(var + 1e-5f);
        #pragma unroll
        for (int j=0;j<8;++j){
          int col = wc*128 + j*16 + c;
          float v = acc[i][j][r];
          int pc = pcol32(col & ~31, j&1, c>>2, c&3);
          nout[mrow + pc] = f2bf((v-mean)*rs*gam[col] + bet[col]);
        }
      }
    }
  }
}

// ---------------------------------------------------------------------------
extern "C" void kernel_launch(void* const* d_in, const int* in_sizes, int n_in,
                              void* d_out, int out_size, void* d_ws, size_t ws_size,
                              hipStream_t stream)
{
  const int*   x    = (const int*)  d_in[0];
  const float* E    = (const float*)d_in[1];
  const float* ln1g = (const float*)d_in[2];
  const float* ln1b = (const float*)d_in[3];
  const float* Wqkv = (const float*)d_in[4];
  const float* Wout = (const float*)d_in[5];
  const float* bout = (const float*)d_in[6];
  const float* ln2g = (const float*)d_in[7];
  const float* ln2b = (const float*)d_in[8];
  const float* W1   = (const float*)d_in[9];
  const float* b1   = (const float*)d_in[10];
  const float* W2   = (const float*)d_in[11];
  const float* b2   = (const float*)d_in[12];
  float* h = (float*)d_out;

  const size_t WQKV = (size_t)LAYERS*1536*256;
  const size_t WOUT = (size_t)LAYERS*256*512;
  const size_t W1T  = (size_t)LAYERS*2048*256;
  const size_t W2T  = (size_t)LAYERS*256*1024;
  u16* wqkv_t = (u16*)d_ws;
  u16* wout_t = wqkv_t + WQKV;
  u16* w1_t   = wout_t + WOUT;
  u16* w2_t   = w1_t   + W1T;
  u16* abase  = w2_t   + W2T;
  const size_t wbytes = (WQKV + WOUT + W1T + W2T) * 2;
  if (ws_size < wbytes + (size_t)1024*3584) return;
  size_t rem = ws_size - wbytes;

  // per-token activation bytes: n(512) + o(1024) + act(2048) bf16 = 3584 B.
  // Mc=32768 -> live set ~150MB, L3-safe.
  int Mc = MCAP;
  while (Mc > 1024 && (size_t)Mc*3584 > rem) Mc >>= 1;
  const int nc = MTOK / Mc;

  u16* n_bf   = abase;                       // [Mc][256]  permuted
  u16* o_bf   = n_bf + (size_t)Mc*256;       // [Mc][512]  permuted
  u16* act_bf = o_bf + (size_t)Mc*512;       // [Mc][1024] permuted

  int tot;
  tot = LAYERS*1536*256; wtrans_kernel<<<(tot+255)/256,256,0,stream>>>(Wqkv, wqkv_t, 256,  1536, tot);
  tot = LAYERS*256*512;  wtrans_kernel<<<(tot+255)/256,256,0,stream>>>(Wout, wout_t, 512,  256,  tot);
  tot = LAYERS*2048*256; wtrans_kernel<<<(tot+255)/256,256,0,stream>>>(W1,   w1_t,   256,  2048, tot);
  tot = LAYERS*256*1024; wtrans_kernel<<<(tot+255)/256,256,0,stream>>>(W2,   w2_t,   1024, 256,  tot);

  for (int cidx=0; cidx<nc; ++cidx){
    float* hc = h + (size_t)cidx*Mc*256;
    const int* xc = x + (size_t)cidx*Mc;
    embed_ln_kernel<<<Mc/4,256,0,stream>>>(xc, E, ln1g, ln1b, hc, n_bf);
    for (int l=0; l<LAYERS; ++l){
      qkv_attn_kernel<<<8*(Mc/128),256,0,stream>>>(
          n_bf, wqkv_t + (size_t)l*1536*256, o_bf, 256);
      gemm_res_ln_kernel<1><<<Mc/64,256,0,stream>>>(
          o_bf, wout_t + (size_t)l*256*512, hc, bout + l*256,
          ln2g + l*256, ln2b + l*256, n_bf, 512);
      gemm_gated_kernel<<<8*(Mc/128),256,0,stream>>>(
          n_bf, w1_t + (size_t)l*2048*256, act_bf, b1 + l*2048, 256);
      if (l < LAYERS-1){
        gemm_res_ln_kernel<1><<<Mc/64,256,0,stream>>>(
            act_bf, w2_t + (size_t)l*256*1024, hc, b2 + l*256,
            ln1g + (l+1)*256, ln1b + (l+1)*256, n_bf, 1024);
      } else {
        gemm_res_ln_kernel<0><<<Mc/64,256,0,stream>>>(
            act_bf, w2_t + (size_t)l*256*1024, hc, b2 + l*256,
            nullptr, nullptr, nullptr, 1024);
      }
    }
  }
}